// Round 8
// baseline (2997.047 us; speedup 1.0000x reference)
//
#include <hip/hip_runtime.h>

typedef _Float16 half_t;
typedef _Float16 half2_t __attribute__((ext_vector_type(2)));
typedef _Float16 half8_t __attribute__((ext_vector_type(8)));
typedef float    f32x4   __attribute__((ext_vector_type(4)));
typedef unsigned int       u32;
typedef u32      u32x4   __attribute__((ext_vector_type(4)));
typedef unsigned short     u16;

#define BB    32      // batch
#define TT    2048    // seq len
#define HH    256     // hidden = input dim
#define G3    768     // 3*H
#define CHUNK 8       // timesteps per protocol transaction
#define NBUF  4       // chunks of buffering per link
#define NSLOT (CHUNK * NBUF)   // 32 ring slots
#define NCK   (TT / CHUNK)     // 256 chunks

// ws layout (bytes), ~6.84 MB total:
//   0        : flags[3][BB] padded 128B each (u32[group] in first 16B)
//   12288    : cons [3][BB] padded 128B each
//   24576    : xg0q [BB][NSLOT][G3] f32   (3145728)
//   3170304  : xg1q [BB][NSLOT][G3] f32   (3145728)
//   6316032  : h0q  [BB][NSLOT][HH] f16   (524288)
#define OFF_CONS 12288
#define OFF_XG0  24576
#define OFF_XG1  3170304
#define OFF_H0   6316032
#define FLAGS_BYTES 24576

__device__ __forceinline__ half2_t f2h2(float a, float b) {
  half2_t r; r.x = (half_t)a; r.y = (half_t)b; return r;
}
__device__ __forceinline__ float sigm(float v) {
  return __builtin_amdgcn_rcpf(1.f + __builtin_amdgcn_exp2f(v * -1.4426950408889634f));
}
__device__ __forceinline__ float tanh_fast(float v) {
  return 1.f - 2.f * __builtin_amdgcn_rcpf(1.f + __builtin_amdgcn_exp2f(v * 2.8853900817779268f));
}
// RELAXED-only wait. No acquire: payload ld/st are themselves agent-scope
// (point-of-coherence) ops, and the producer posts the flag only after a
// vmcnt(0) drain of its payload stores — so a plain UC poll + compiler
// barrier is sufficient. Avoids the per-poll L2 invalidate (buffer_inv)
// an agent-scope acquire emits (R7 theory: 4 invalidates/chunk/block).
__device__ __forceinline__ void wait_ge(u32* p, u32 v) {
  while (__hip_atomic_load(p, __ATOMIC_RELAXED, __HIP_MEMORY_SCOPE_AGENT) < v)
    __builtin_amdgcn_s_sleep(1);
  asm volatile("" ::: "memory");
}
__device__ __forceinline__ float ld_f32_agent(const float* p) {
  return __hip_atomic_load(p, __ATOMIC_RELAXED, __HIP_MEMORY_SCOPE_AGENT);
}
__device__ __forceinline__ u32 ld_u32_agent(const u32* p) {
  return __hip_atomic_load(p, __ATOMIC_RELAXED, __HIP_MEMORY_SCOPE_AGENT);
}
__device__ __forceinline__ void st_f32_agent(float* p, float v) {
  __hip_atomic_store(p, v, __ATOMIC_RELAXED, __HIP_MEMORY_SCOPE_AGENT);
}
__device__ __forceinline__ void st_u16_agent(u16* p, u16 v) {
  __hip_atomic_store(p, v, __ATOMIC_RELAXED, __HIP_MEMORY_SCOPE_AGENT);
}
__device__ __forceinline__ void st_u32_relaxed(u32* p, u32 v) {
  __hip_atomic_store(p, v, __ATOMIC_RELAXED, __HIP_MEMORY_SCOPE_AGENT);
}
// LDS-visibility barrier WITHOUT vmcnt(0): global stores stay in flight.
__device__ __forceinline__ void barrier_lds() {
  asm volatile("s_waitcnt lgkmcnt(0)" ::: "memory");
  __builtin_amdgcn_s_barrier();
  asm volatile("" ::: "memory");
}

__device__ __forceinline__ void dot3(const half2_t* hrow, const u32 (&w)[3][64],
                                     float& a0, float& a1, float& a2) {
  const float4* hv4 = (const float4*)hrow;
#pragma unroll
  for (int j4 = 0; j4 < 16; ++j4) {
    float4 q = hv4[j4];
    half2_t hh[4];
    hh[0] = __builtin_bit_cast(half2_t, q.x);
    hh[1] = __builtin_bit_cast(half2_t, q.y);
    hh[2] = __builtin_bit_cast(half2_t, q.z);
    hh[3] = __builtin_bit_cast(half2_t, q.w);
#pragma unroll
    for (int u = 0; u < 4; ++u) {
      const int idx = j4 * 4 + u;
      a0 = __builtin_amdgcn_fdot2(__builtin_bit_cast(half2_t, w[0][idx]), hh[u], a0, false);
      a1 = __builtin_amdgcn_fdot2(__builtin_bit_cast(half2_t, w[1][idx]), hh[u], a1, false);
      a2 = __builtin_amdgcn_fdot2(__builtin_bit_cast(half2_t, w[2][idx]), hh[u], a2, false);
    }
  }
}

// 128 blocks: blockIdx = stage*32 + chain.
//   stage 0: xg0 = Wih0@x_t + bih0       stage 1: GRU cell layer 0 (Whh0)
//   stage 2: xg1 = Wih1@h0_t + bih1      stage 3: GRU cell layer 1 (Whh1) -> out
// R8: all protocol ops RELAXED (no acquire L2-invalidates / release fences);
// rec stages preload ALL 24 gate values per chunk at the top (UC loads in
// parallel, compiler-ordered) so no per-step MALL/HBM latency sits on the
// h_t -> h_{t+1} serial chain.
__global__ __launch_bounds__(512) __attribute__((amdgpu_waves_per_eu(2, 2)))
void gru_pipe(const float* __restrict__ x,     // fp32 [B][T][H]
              const float* __restrict__ Wih,   // fp32 [2][768][256]
              const float* __restrict__ Whh,   // fp32 [2][768][256]
              const float* __restrict__ bih,   // fp32 [2][768]
              const float* __restrict__ bhh,   // fp32 [2][768]
              float* __restrict__ out,         // fp32 [B][T][H]
              uint8_t* __restrict__ ws)
{
  const int stage = blockIdx.x >> 5;
  const int chain = blockIdx.x & 31;
  const int tid   = threadIdx.x;
  const int l     = stage >> 1; // layer
  const bool rec  = (stage & 1);

  u32*    flags = (u32*)ws;
  u32*    cons  = (u32*)(ws + OFF_CONS);
  float*  xg0q  = (float*)(ws + OFF_XG0);
  float*  xg1q  = (float*)(ws + OFF_XG1);
  half_t* h0q   = (half_t*)(ws + OFF_H0);

  const float* Wm = (rec ? Whh : Wih) + (size_t)l * G3 * HH;
  const float* bv = (rec ? bhh : bih) + (size_t)l * G3;

  __shared__ __align__(16) half2_t hb4[CHUNK][128];
  if (tid < 128) {
    half2_t z; z.x = (half_t)0.f; z.y = (half_t)0.f;
#pragma unroll
    for (int s = 0; s < CHUNK; ++s) hb4[s][tid] = z;
  }

  float* xgq_in  = (stage == 1) ? xg0q : xg1q;
  float* xgq_out = (stage == 0) ? xg0q : xg1q;
  u32* flag_in   = flags + ((size_t)((stage - 1) * BB + chain)) * 32;  // stage>0
  u32* flag_out  = flags + ((size_t)(stage * BB + chain)) * 32;        // stage<3
  u32* cons_in   = cons + ((size_t)((stage - 1) * BB + chain)) * 32;
  u32* cons_out  = cons + ((size_t)(stage * BB + chain)) * 32;

  if (!rec) {
    // ================== !REC: fdot2 GEMV path ==============================
    const int i = (tid >> 6) * 32 + (tid & 31);
    const int c = (tid >> 5) & 1;
    u32   w[3][64];
    float bs[3];
#pragma unroll
    for (int r = 0; r < 3; ++r) {
      const int row = r * 256 + i;
      const float4* wp = (const float4*)(Wm + (size_t)row * HH + c * 128);
#pragma unroll
      for (int j = 0; j < 32; ++j) {
        float4 v = wp[j];
        w[r][2 * j]     = __builtin_bit_cast(u32, f2h2(v.x, v.y));
        w[r][2 * j + 1] = __builtin_bit_cast(u32, f2h2(v.z, v.w));
      }
      bs[r] = bv[row];
    }
#pragma unroll
    for (int r = 0; r < 3; ++r)
#pragma unroll
      for (int j = 0; j < 64; ++j)
        asm volatile("" : "+v"(w[r][j]));

    half2_t xreg[CHUNK];
    if (stage == 0 && tid < 128) {
#pragma unroll
      for (int s = 0; s < CHUNK; ++s) {
        float2 v = ((const float2*)(x + (size_t)(chain * TT + s) * HH))[tid];
        xreg[s] = f2h2(v.x, v.y);
      }
    }
    __syncthreads();

    for (int ck = 0; ck < NCK; ++ck) {
      const int g = ck & (NBUF - 1);
      const size_t qs = (size_t)chain * NSLOT + g * CHUNK;

      if (stage > 0 && tid == 0)                 wait_ge(flag_in + g, (u32)(ck + 1));
      if (ck >= NBUF && tid == 256)              wait_ge(cons_out, (u32)(ck - NBUF + 1));
      __syncthreads();   // join pollers; drains PREV chunk's stores (vmcnt 0)

      if (tid == 0 && ck > 0)   // deferred release of previous chunk (relaxed:
        st_u32_relaxed(flag_out + ((ck - 1) & (NBUF - 1)), (u32)ck);  // drained above)

      if (stage == 0) {
        if (tid < 128) {
#pragma unroll
          for (int s = 0; s < CHUNK; ++s) hb4[s][tid] = xreg[s];
        }
      } else {  // stage 2: h0 chunk from queue
        if (tid < 128) {
#pragma unroll
          for (int s = 0; s < CHUNK; ++s) {
            u32 v = ld_u32_agent((const u32*)(h0q + (qs + s) * HH) + tid);
            hb4[s][tid] = __builtin_bit_cast(half2_t, v);
          }
        }
      }
      barrier_lds();   // hb4 visible
      if (stage == 2 && tid == 0)   // early credit: stage1 may overwrite group
        st_u32_relaxed(cons_in, (u32)(ck + 1));
      if (stage == 0 && tid < 128 && ck + 1 < NCK) {
#pragma unroll
        for (int s = 0; s < CHUNK; ++s) {
          float2 v = ((const float2*)(x + (size_t)(chain * TT + (ck + 1) * CHUNK + s) * HH))[tid];
          xreg[s] = f2h2(v.x, v.y);
        }
      }
#pragma unroll
      for (int s = 0; s < CHUNK; ++s) {
        float a0 = 0.f, a1 = 0.f, a2 = 0.f;
        dot3(&hb4[s][c * 64], w, a0, a1, a2);
        a0 += __shfl_xor(a0, 32, 64);
        a1 += __shfl_xor(a1, 32, 64);
        a2 += __shfl_xor(a2, 32, 64);
        if (c == 0) {
          float* qo = xgq_out + (qs + s) * G3;
          st_f32_agent(qo + i,       a0 + bs[0]);
          st_f32_agent(qo + 256 + i, a1 + bs[1]);
          st_f32_agent(qo + 512 + i, a2 + bs[2]);
        }
      }
    }
    __syncthreads();   // drain last chunk's stores
    if (tid == 0)
      st_u32_relaxed(flag_out + ((NCK - 1) & (NBUF - 1)), (u32)NCK);
  } else {
    // ================== REC: MFMA GRU-cell path ============================
    const int wv = tid >> 6;        // wave 0..7
    const int lane = tid & 63;
    const int lr = lane & 15;       // N-col within tile
    const int g4 = lane >> 4;       // K-group 0..3
    const int j0 = wv * 16 + lr;    // 0..127
    const bool act = (g4 < 2);      // epilogue-active lanes
    const int idx = g4 * 128 + j0;  // h index owned (g4<2): covers 0..255

    // B-frags: wf[tt][kk], lane holds W[tt*128+j0][kk*32+g4*8+j], j=0..7
    u32x4 wf[6][8];
#pragma unroll
    for (int tt = 0; tt < 6; ++tt) {
      const int row = tt * 128 + j0;
#pragma unroll
      for (int kk = 0; kk < 8; ++kk) {
        const float4* p = (const float4*)(Wm + (size_t)row * HH + kk * 32 + g4 * 8);
        float4 qa = p[0], qb = p[1];
        u32x4 v;
        v.x = __builtin_bit_cast(u32, f2h2(qa.x, qa.y));
        v.y = __builtin_bit_cast(u32, f2h2(qa.z, qa.w));
        v.z = __builtin_bit_cast(u32, f2h2(qb.x, qb.y));
        v.w = __builtin_bit_cast(u32, f2h2(qb.z, qb.w));
        wf[tt][kk] = v;
      }
    }
#pragma unroll
    for (int tt = 0; tt < 6; ++tt)
#pragma unroll
      for (int kk = 0; kk < 8; ++kk)
        asm volatile("" : "+v"(wf[tt][kk]));   // pin: no remat inside t-loop

    float bR = 0.f, bZ = 0.f, bN = 0.f;
    if (act) { bR = bv[idx]; bZ = bv[256 + idx]; bN = bv[512 + idx]; }
    float hprev = 0.f;
    __syncthreads();

    for (int ck = 0; ck < NCK; ++ck) {
      const int g = ck & (NBUF - 1);
      const size_t qs = (size_t)chain * NSLOT + g * CHUNK;

      if (tid == 0)                              wait_ge(flag_in + g, (u32)(ck + 1));
      if (stage < 3 && ck >= NBUF && tid == 256) wait_ge(cons_out, (u32)(ck - NBUF + 1));
      __syncthreads();   // join pollers; drains PREV chunk's stores

      if (tid == 0 && ck > 0) {   // deferred release + upstream credit (relaxed)
        if (stage < 3)
          st_u32_relaxed(flag_out + ((ck - 1) & (NBUF - 1)), (u32)ck);
        st_u32_relaxed(cons_in, (u32)ck);
      }

      // ---- preload ALL gates for the chunk (parallel UC loads; latency
      //      amortized over 8 steps, off the h_t->h_{t+1} serial chain) ----
      const float* q0 = xgq_in + qs * G3;
      float xr[CHUNK], xz[CHUNK], xn[CHUNK];
      if (act) {
#pragma unroll
        for (int s = 0; s < CHUNK; ++s) {
          const float* qn = q0 + s * G3;
          xr[s] = ld_f32_agent(qn + idx);
          xz[s] = ld_f32_agent(qn + 256 + idx);
          xn[s] = ld_f32_agent(qn + 512 + idx);
        }
      }
#pragma unroll
      for (int s = 0; s < CHUNK; ++s) {
        f32x4 acc[6];
#pragma unroll
        for (int tt = 0; tt < 6; ++tt) acc[tt] = (f32x4){0.f, 0.f, 0.f, 0.f};
        const float4* ab = (const float4*)((const half_t*)&hb4[s & 1][0]);
#pragma unroll
        for (int kk = 0; kk < 8; ++kk) {
          half8_t af = __builtin_bit_cast(half8_t, ab[kk * 4 + g4]);  // h[kk*32+g4*8 ..+8)
#pragma unroll
          for (int tt = 0; tt < 6; ++tt)
            acc[tt] = __builtin_amdgcn_mfma_f32_16x16x32_f16(
                af, __builtin_bit_cast(half8_t, wf[tt][kk]), acc[tt], 0, 0, 0);
        }
        if (act) {
          float aR = g4 ? acc[1][0] : acc[0][0];
          float aZ = g4 ? acc[3][0] : acc[2][0];
          float aN = g4 ? acc[5][0] : acc[4][0];
          float r    = sigm(xr[s] + aR + bR);
          float z    = sigm(xz[s] + aZ + bZ);
          float n    = tanh_fast(xn[s] + r * (aN + bN));
          float hnew = n + z * (hprev - n);
          hprev = hnew;
          ((half_t*)&hb4[(s + 1) & 1][0])[idx] = (half_t)hnew;   // next step's A
          if (stage == 1) {
            half_t hv = (half_t)hnew;
            st_u16_agent((u16*)(h0q + (qs + s) * HH + idx),
                         __builtin_bit_cast(u16, hv));
          } else {
            out[(size_t)(chain * TT + ck * CHUNK + s) * HH + idx] = hnew;
          }
        }
        if (s < CHUNK - 1) barrier_lds();   // h visible; stores stay in flight
      }
    }
    __syncthreads();   // drain last chunk's stores
    if (tid == 0 && stage < 3)
      st_u32_relaxed(flag_out + ((NCK - 1) & (NBUF - 1)), (u32)NCK);
  }
}

extern "C" void kernel_launch(void* const* d_in, const int* in_sizes, int n_in,
                              void* d_out, int out_size, void* d_ws, size_t ws_size,
                              hipStream_t stream) {
  hipMemsetAsync(d_ws, 0, FLAGS_BYTES, stream);
  hipLaunchKernelGGL(gru_pipe, dim3(128), dim3(512), 0, stream,
                     (const float*)d_in[0], (const float*)d_in[1], (const float*)d_in[2],
                     (const float*)d_in[3], (const float*)d_in[4],
                     (float*)d_out, (uint8_t*)d_ws);
}

// Round 9
// 2570.517 us; speedup vs baseline: 1.1659x; 1.1659x over previous
//
#include <hip/hip_runtime.h>

typedef _Float16 half_t;
typedef _Float16 half2_t __attribute__((ext_vector_type(2)));
typedef _Float16 half8_t __attribute__((ext_vector_type(8)));
typedef float    f32x4   __attribute__((ext_vector_type(4)));
typedef unsigned int       u32;
typedef u32      u32x4   __attribute__((ext_vector_type(4)));
typedef unsigned short     u16;

#define BB    32      // batch
#define TT    2048    // seq len
#define HH    256     // hidden = input dim
#define G3    768     // 3*H
#define CHUNK 4       // timesteps per protocol transaction
#define NBUF  8       // chunks of buffering per link (slack >> RTT)
#define NSLOT (CHUNK * NBUF)   // 32 ring slots (same ws footprint as R5-R8)
#define NCK   (TT / CHUNK)     // 512 chunks

// ws layout (bytes), ~6.84 MB total:
//   0        : flags[3][BB] padded 128B each (u32[group] in first 32B)
//   12288    : cons [3][BB] padded 128B each
//   24576    : xg0q [BB][NSLOT][G3] f32   (3145728)
//   3170304  : xg1q [BB][NSLOT][G3] f32   (3145728)
//   6316032  : h0q  [BB][NSLOT][HH] f16   (524288)
#define OFF_CONS 12288
#define OFF_XG0  24576
#define OFF_XG1  3170304
#define OFF_H0   6316032
#define FLAGS_BYTES 24576

__device__ __forceinline__ half2_t f2h2(float a, float b) {
  half2_t r; r.x = (half_t)a; r.y = (half_t)b; return r;
}
__device__ __forceinline__ float sigm(float v) {
  return __builtin_amdgcn_rcpf(1.f + __builtin_amdgcn_exp2f(v * -1.4426950408889634f));
}
__device__ __forceinline__ float tanh_fast(float v) {
  return 1.f - 2.f * __builtin_amdgcn_rcpf(1.f + __builtin_amdgcn_exp2f(v * 2.8853900817779268f));
}
// RELAXED-only wait: producer posts flags only after a vmcnt(0) drain of its
// UC payload stores, and payload accesses are themselves agent-scope UC ops,
// so no acquire (and its L2 invalidate) is needed.
__device__ __forceinline__ void wait_ge(u32* p, u32 v) {
  while (__hip_atomic_load(p, __ATOMIC_RELAXED, __HIP_MEMORY_SCOPE_AGENT) < v)
    __builtin_amdgcn_s_sleep(1);
  asm volatile("" ::: "memory");
}
__device__ __forceinline__ float ld_f32_agent(const float* p) {
  return __hip_atomic_load(p, __ATOMIC_RELAXED, __HIP_MEMORY_SCOPE_AGENT);
}
__device__ __forceinline__ u32 ld_u32_agent(const u32* p) {
  return __hip_atomic_load(p, __ATOMIC_RELAXED, __HIP_MEMORY_SCOPE_AGENT);
}
__device__ __forceinline__ void st_f32_agent(float* p, float v) {
  __hip_atomic_store(p, v, __ATOMIC_RELAXED, __HIP_MEMORY_SCOPE_AGENT);
}
__device__ __forceinline__ void st_u16_agent(u16* p, u16 v) {
  __hip_atomic_store(p, v, __ATOMIC_RELAXED, __HIP_MEMORY_SCOPE_AGENT);
}
__device__ __forceinline__ void st_u32_relaxed(u32* p, u32 v) {
  __hip_atomic_store(p, v, __ATOMIC_RELAXED, __HIP_MEMORY_SCOPE_AGENT);
}
// LDS-visibility barrier WITHOUT vmcnt(0): global stores stay in flight.
__device__ __forceinline__ void barrier_lds() {
  asm volatile("s_waitcnt lgkmcnt(0)" ::: "memory");
  __builtin_amdgcn_s_barrier();
  asm volatile("" ::: "memory");
}

__device__ __forceinline__ void dot3(const half2_t* hrow, const u32 (&w)[3][64],
                                     float& a0, float& a1, float& a2) {
  const float4* hv4 = (const float4*)hrow;
#pragma unroll
  for (int j4 = 0; j4 < 16; ++j4) {
    float4 q = hv4[j4];
    half2_t hh[4];
    hh[0] = __builtin_bit_cast(half2_t, q.x);
    hh[1] = __builtin_bit_cast(half2_t, q.y);
    hh[2] = __builtin_bit_cast(half2_t, q.z);
    hh[3] = __builtin_bit_cast(half2_t, q.w);
#pragma unroll
    for (int u = 0; u < 4; ++u) {
      const int idx = j4 * 4 + u;
      a0 = __builtin_amdgcn_fdot2(__builtin_bit_cast(half2_t, w[0][idx]), hh[u], a0, false);
      a1 = __builtin_amdgcn_fdot2(__builtin_bit_cast(half2_t, w[1][idx]), hh[u], a1, false);
      a2 = __builtin_amdgcn_fdot2(__builtin_bit_cast(half2_t, w[2][idx]), hh[u], a2, false);
    }
  }
}

// 128 blocks: blockIdx = stage*32 + chain.
//   stage 0: xg0 = Wih0@x_t + bih0       stage 1: GRU cell layer 0 (Whh0)
//   stage 2: xg1 = Wih1@h0_t + bih1      stage 3: GRU cell layer 1 (Whh1) -> out
// R9: the system is LATENCY-bound around the protocol cycle (cross-round
// evidence: R6/R7/R8 fixed LDS/ALU/loads, cadence never moved). Fix: amortize
// flag/credit RTTs over NBUF=8 chunks of slack — CHUNK=4, NBUF=8 (same
// NSLOT=32 footprint), IMMEDIATE end-of-chunk release (deferred release
// consumed a chunk of slack per hop). cadence floor -> max stage proc.
__global__ __launch_bounds__(512) __attribute__((amdgpu_waves_per_eu(2, 2)))
void gru_pipe(const float* __restrict__ x,     // fp32 [B][T][H]
              const float* __restrict__ Wih,   // fp32 [2][768][256]
              const float* __restrict__ Whh,   // fp32 [2][768][256]
              const float* __restrict__ bih,   // fp32 [2][768]
              const float* __restrict__ bhh,   // fp32 [2][768]
              float* __restrict__ out,         // fp32 [B][T][H]
              uint8_t* __restrict__ ws)
{
  const int stage = blockIdx.x >> 5;
  const int chain = blockIdx.x & 31;
  const int tid   = threadIdx.x;
  const int l     = stage >> 1; // layer
  const bool rec  = (stage & 1);

  u32*    flags = (u32*)ws;
  u32*    cons  = (u32*)(ws + OFF_CONS);
  float*  xg0q  = (float*)(ws + OFF_XG0);
  float*  xg1q  = (float*)(ws + OFF_XG1);
  half_t* h0q   = (half_t*)(ws + OFF_H0);

  const float* Wm = (rec ? Whh : Wih) + (size_t)l * G3 * HH;
  const float* bv = (rec ? bhh : bih) + (size_t)l * G3;

  __shared__ __align__(16) half2_t hb4[CHUNK][128];
  if (tid < 128) {
    half2_t z; z.x = (half_t)0.f; z.y = (half_t)0.f;
#pragma unroll
    for (int s = 0; s < CHUNK; ++s) hb4[s][tid] = z;
  }

  float* xgq_in  = (stage == 1) ? xg0q : xg1q;
  float* xgq_out = (stage == 0) ? xg0q : xg1q;
  u32* flag_in   = flags + ((size_t)((stage - 1) * BB + chain)) * 32;  // stage>0
  u32* flag_out  = flags + ((size_t)(stage * BB + chain)) * 32;        // stage<3
  u32* cons_in   = cons + ((size_t)((stage - 1) * BB + chain)) * 32;
  u32* cons_out  = cons + ((size_t)(stage * BB + chain)) * 32;

  if (!rec) {
    // ================== !REC: fdot2 GEMV path ==============================
    const int i = (tid >> 6) * 32 + (tid & 31);
    const int c = (tid >> 5) & 1;
    u32   w[3][64];
    float bs[3];
#pragma unroll
    for (int r = 0; r < 3; ++r) {
      const int row = r * 256 + i;
      const float4* wp = (const float4*)(Wm + (size_t)row * HH + c * 128);
#pragma unroll
      for (int j = 0; j < 32; ++j) {
        float4 v = wp[j];
        w[r][2 * j]     = __builtin_bit_cast(u32, f2h2(v.x, v.y));
        w[r][2 * j + 1] = __builtin_bit_cast(u32, f2h2(v.z, v.w));
      }
      bs[r] = bv[row];
    }
#pragma unroll
    for (int r = 0; r < 3; ++r)
#pragma unroll
      for (int j = 0; j < 64; ++j)
        asm volatile("" : "+v"(w[r][j]));

    half2_t xreg[CHUNK];
    if (stage == 0 && tid < 128) {
#pragma unroll
      for (int s = 0; s < CHUNK; ++s) {
        float2 v = ((const float2*)(x + (size_t)(chain * TT + s) * HH))[tid];
        xreg[s] = f2h2(v.x, v.y);
      }
    }
    __syncthreads();

    for (int ck = 0; ck < NCK; ++ck) {
      const int g = ck & (NBUF - 1);
      const size_t qs = (size_t)chain * NSLOT + g * CHUNK;

      // ---- parallel polls (two waves), then join ----
      if (stage > 0 && tid == 0)                 wait_ge(flag_in + g, (u32)(ck + 1));
      if (ck >= NBUF && tid == 256)              wait_ge(cons_out, (u32)(ck - NBUF + 1));
      __syncthreads();

      if (stage == 0) {
        if (tid < 128) {
#pragma unroll
          for (int s = 0; s < CHUNK; ++s) hb4[s][tid] = xreg[s];
        }
      } else {  // stage 2: h0 chunk from queue
        if (tid < 128) {
#pragma unroll
          for (int s = 0; s < CHUNK; ++s) {
            u32 v = ld_u32_agent((const u32*)(h0q + (qs + s) * HH) + tid);
            hb4[s][tid] = __builtin_bit_cast(half2_t, v);
          }
        }
      }
      barrier_lds();   // hb4 visible (UC loads complete before their ds_write)
      if (stage == 2 && tid == 0)   // early credit: stage1 may overwrite group
        st_u32_relaxed(cons_in, (u32)(ck + 1));
      if (stage == 0 && tid < 128 && ck + 1 < NCK) {
#pragma unroll
        for (int s = 0; s < CHUNK; ++s) {
          float2 v = ((const float2*)(x + (size_t)(chain * TT + (ck + 1) * CHUNK + s) * HH))[tid];
          xreg[s] = f2h2(v.x, v.y);
        }
      }
#pragma unroll
      for (int s = 0; s < CHUNK; ++s) {
        float a0 = 0.f, a1 = 0.f, a2 = 0.f;
        dot3(&hb4[s][c * 64], w, a0, a1, a2);
        a0 += __shfl_xor(a0, 32, 64);
        a1 += __shfl_xor(a1, 32, 64);
        a2 += __shfl_xor(a2, 32, 64);
        if (c == 0) {
          float* qo = xgq_out + (qs + s) * G3;
          st_f32_agent(qo + i,       a0 + bs[0]);
          st_f32_agent(qo + 256 + i, a1 + bs[1]);
          st_f32_agent(qo + 512 + i, a2 + bs[2]);
        }
      }
      // ---- immediate release: drain this chunk's stores, post flag ----
      __syncthreads();   // per-wave vmcnt(0) before s_barrier -> stores acked
      if (tid == 0)
        st_u32_relaxed(flag_out + g, (u32)(ck + 1));
    }
  } else {
    // ================== REC: MFMA GRU-cell path ============================
    const int wv = tid >> 6;        // wave 0..7
    const int lane = tid & 63;
    const int lr = lane & 15;       // N-col within tile
    const int g4 = lane >> 4;       // K-group 0..3
    const int j0 = wv * 16 + lr;    // 0..127
    const bool act = (g4 < 2);      // epilogue-active lanes
    const int idx = g4 * 128 + j0;  // h index owned (g4<2): covers 0..255

    // B-frags: wf[tt][kk], lane holds W[tt*128+j0][kk*32+g4*8+j], j=0..7
    u32x4 wf[6][8];
#pragma unroll
    for (int tt = 0; tt < 6; ++tt) {
      const int row = tt * 128 + j0;
#pragma unroll
      for (int kk = 0; kk < 8; ++kk) {
        const float4* p = (const float4*)(Wm + (size_t)row * HH + kk * 32 + g4 * 8);
        float4 qa = p[0], qb = p[1];
        u32x4 v;
        v.x = __builtin_bit_cast(u32, f2h2(qa.x, qa.y));
        v.y = __builtin_bit_cast(u32, f2h2(qa.z, qa.w));
        v.z = __builtin_bit_cast(u32, f2h2(qb.x, qb.y));
        v.w = __builtin_bit_cast(u32, f2h2(qb.z, qb.w));
        wf[tt][kk] = v;
      }
    }
#pragma unroll
    for (int tt = 0; tt < 6; ++tt)
#pragma unroll
      for (int kk = 0; kk < 8; ++kk)
        asm volatile("" : "+v"(wf[tt][kk]));   // pin: no remat inside t-loop

    float bR = 0.f, bZ = 0.f, bN = 0.f;
    if (act) { bR = bv[idx]; bZ = bv[256 + idx]; bN = bv[512 + idx]; }
    float hprev = 0.f;
    __syncthreads();

    for (int ck = 0; ck < NCK; ++ck) {
      const int g = ck & (NBUF - 1);
      const size_t qs = (size_t)chain * NSLOT + g * CHUNK;

      if (tid == 0)                              wait_ge(flag_in + g, (u32)(ck + 1));
      if (stage < 3 && ck >= NBUF && tid == 256) wait_ge(cons_out, (u32)(ck - NBUF + 1));
      __syncthreads();

      // ---- preload all gates for the chunk (12 parallel UC loads) ----
      const float* q0 = xgq_in + qs * G3;
      float xr[CHUNK], xz[CHUNK], xn[CHUNK];
      if (act) {
#pragma unroll
        for (int s = 0; s < CHUNK; ++s) {
          const float* qn = q0 + s * G3;
          xr[s] = ld_f32_agent(qn + idx);
          xz[s] = ld_f32_agent(qn + 256 + idx);
          xn[s] = ld_f32_agent(qn + 512 + idx);
        }
      }
#pragma unroll
      for (int s = 0; s < CHUNK; ++s) {
        f32x4 acc[6];
#pragma unroll
        for (int tt = 0; tt < 6; ++tt) acc[tt] = (f32x4){0.f, 0.f, 0.f, 0.f};
        const float4* ab = (const float4*)((const half_t*)&hb4[s & 1][0]);
#pragma unroll
        for (int kk = 0; kk < 8; ++kk) {
          half8_t af = __builtin_bit_cast(half8_t, ab[kk * 4 + g4]);  // h[kk*32+g4*8 ..+8)
#pragma unroll
          for (int tt = 0; tt < 6; ++tt)
            acc[tt] = __builtin_amdgcn_mfma_f32_16x16x32_f16(
                af, __builtin_bit_cast(half8_t, wf[tt][kk]), acc[tt], 0, 0, 0);
        }
        if (act) {
          float aR = g4 ? acc[1][0] : acc[0][0];
          float aZ = g4 ? acc[3][0] : acc[2][0];
          float aN = g4 ? acc[5][0] : acc[4][0];
          float r    = sigm(xr[s] + aR + bR);
          float z    = sigm(xz[s] + aZ + bZ);
          float n    = tanh_fast(xn[s] + r * (aN + bN));
          float hnew = n + z * (hprev - n);
          hprev = hnew;
          ((half_t*)&hb4[(s + 1) & 1][0])[idx] = (half_t)hnew;   // next step's A
          if (stage == 1) {
            half_t hv = (half_t)hnew;
            st_u16_agent((u16*)(h0q + (qs + s) * HH + idx),
                         __builtin_bit_cast(u16, hv));
          } else {
            out[(size_t)(chain * TT + ck * CHUNK + s) * HH + idx] = hnew;
          }
        }
        if (s < CHUNK - 1) barrier_lds();   // h visible; stores stay in flight
      }
      // ---- immediate release: drain stores, post flag + upstream credit ----
      __syncthreads();   // vmcnt(0) per wave: h0q/out stores acked, gate loads done
      if (tid == 0) {
        if (stage < 3)
          st_u32_relaxed(flag_out + g, (u32)(ck + 1));
        st_u32_relaxed(cons_in, (u32)(ck + 1));
      }
    }
  }
}

extern "C" void kernel_launch(void* const* d_in, const int* in_sizes, int n_in,
                              void* d_out, int out_size, void* d_ws, size_t ws_size,
                              hipStream_t stream) {
  hipMemsetAsync(d_ws, 0, FLAGS_BYTES, stream);
  hipLaunchKernelGGL(gru_pipe, dim3(128), dim3(512), 0, stream,
                     (const float*)d_in[0], (const float*)d_in[1], (const float*)d_in[2],
                     (const float*)d_in[3], (const float*)d_in[4],
                     (float*)d_out, (uint8_t*)d_ws);
}